// Round 1
// baseline (195.614 us; speedup 1.0000x reference)
//
#include <hip/hip_runtime.h>
#include <math.h>

#define CH 16
#define DIM 8
#define ROW 128            // CH*DIM
#define TILE_ROWS 64
#define BLK 512
#define NBLOCKS 512

// ---------------------------------------------------------------------------
// Cayley sign for Cl(3,0): e_a * e_b = csign(a,b) * e_{a^b}.  q=0 -> no metric
// flips; only the reordering sign matters.
// ---------------------------------------------------------------------------
__device__ __forceinline__ float csign(int a, int b) {
    int s = 0;
    int aa = a >> 1;
    while (aa) { s ^= (__popc(aa & b) & 1); aa >>= 1; }
    return s ? -1.0f : 1.0f;
}

// ---------------------------------------------------------------------------
// Precompute kernel (1 block, 256 threads):
//   ws[0      .. 1024)  : M[c][k][m]   -- per-channel 8x8 sandwich matrix
//   ws[1024 .. 17408)   : W2T[in][out] -- 128x128 CliffordLinear matrix,
//                          out[b,out] = sum_in g[b,in] * W2T[in*128+out]
// ---------------------------------------------------------------------------
__global__ void precompute_kernel(const float* __restrict__ rotor,
                                  const float* __restrict__ w,
                                  float* __restrict__ ws)
{
    const int t = threadIdx.x;

    if (t < CH) {
        const int c = t;
        float r[8];
        float nn = 0.f;
        #pragma unroll
        for (int i = 0; i < 8; ++i) { r[i] = rotor[c * 8 + i]; nn += r[i] * r[i]; }
        const float inv = rsqrtf(nn + 1e-6f);
        #pragma unroll
        for (int i = 0; i < 8; ++i) r[i] *= inv;

        // reversion signs per blade (grades 0..3): (-1)^{g(g-1)/2}
        const float REVv[8] = {1.f, 1.f, 1.f, -1.f, 1.f, -1.f, -1.f, -1.f};
        float rr[8];
        #pragma unroll
        for (int j = 0; j < 8; ++j) rr[j] = r[j] * REVv[j];

        float L[8][8], R[8][8];
        #pragma unroll
        for (int a = 0; a < 8; ++a)
            #pragma unroll
            for (int b = 0; b < 8; ++b) { L[a][b] = 0.f; R[a][b] = 0.f; }

        // t_k = sum_i r_i x_j C[i,j,k]  -> L[k][j] += r[i]*s, k=i^j
        // y_k = sum_j t_i rr_j C[i,j,k] -> R[k][i] += rr[j]*s, k=i^j
        #pragma unroll
        for (int i = 0; i < 8; ++i)
            #pragma unroll
            for (int j = 0; j < 8; ++j) {
                const float s = csign(i, j);
                L[i ^ j][j] += r[i] * s;
                R[i ^ j][i] += rr[j] * s;
            }

        // M = R @ L
        #pragma unroll
        for (int k = 0; k < 8; ++k)
            #pragma unroll
            for (int m = 0; m < 8; ++m) {
                float acc = 0.f;
                #pragma unroll
                for (int i = 0; i < 8; ++i) acc += R[k][i] * L[i][m];
                ws[c * 64 + k * 8 + m] = acc;
            }
    }

    // W2T[in*128 + out] = w[o][ci][kb^j] * csign(kb^j, j),
    //   in = ci*8 + j, out = o*8 + kb
    for (int idx = t; idx < ROW * ROW; idx += blockDim.x) {
        const int in  = idx >> 7;
        const int out = idx & 127;
        const int j  = in & 7,  ci = in >> 3;
        const int kb = out & 7, o  = out >> 3;
        const int i  = kb ^ j;
        ws[1024 + idx] = w[(o * CH + ci) * 8 + i] * csign(i, j);
    }
}

// ---------------------------------------------------------------------------
// Fused main kernel: per 64-row tile:
//   1) per (row, channel): blade-norm LN -> 8x8 rotor matrix -> exact GELU
//      into LDS g-tile [64][128]
//   2) 64x128 = g[64][128] @ W2T[128][128] GEMM from LDS, 4x4 microtile/thread
// ---------------------------------------------------------------------------
__global__ __launch_bounds__(BLK) void fused_kernel(
        const float* __restrict__ x,
        const float* __restrict__ ln_scale,
        const float* __restrict__ bias,
        const float* __restrict__ ws,
        float* __restrict__ out,
        int ntiles)
{
    extern __shared__ float smem[];
    float* sW2T   = smem;                         // 16384 floats
    float* sG     = smem + 16384;                 // 8192 floats (64x128)
    float* sM     = smem + 16384 + 8192;          // 1024 floats
    float* sBias  = sM + 1024;                    // 128 floats
    float* sScale = sBias + 128;                  // 16 floats

    const int t = threadIdx.x;

    for (int i = t; i < (ROW * ROW) / 4; i += BLK)
        ((float4*)sW2T)[i] = ((const float4*)(ws + 1024))[i];
    for (int i = t; i < 1024 / 4; i += BLK)
        ((float4*)sM)[i] = ((const float4*)ws)[i];
    if (t < 32) ((float4*)sBias)[t] = ((const float4*)bias)[t];
    if (t < 16) sScale[t] = ln_scale[t];
    __syncthreads();

    const int mr = t >> 5;        // 0..15 -> row group
    const int mc = t & 31;        // 0..31 -> col group
    const int rb = mr * 4;
    const int cb = mc * 4;

    for (int tile = blockIdx.x; tile < ntiles; tile += gridDim.x) {
        const size_t row0 = (size_t)tile * TILE_ROWS;

        // ---- preprocess: LN -> rotor sandwich (8x8 matvec) -> GELU -> LDS
        for (int p = t; p < TILE_ROWS * CH; p += BLK) {
            const int r = p >> 4;
            const int c = p & 15;
            const float4* xp = (const float4*)(x + ((row0 + r) * CH + c) * DIM);
            const float4 a = xp[0];
            const float4 b = xp[1];
            const float nn = a.x*a.x + a.y*a.y + a.z*a.z + a.w*a.w
                           + b.x*b.x + b.y*b.y + b.z*b.z + b.w*b.w;
            const float inv = sScale[c] * rsqrtf(nn + 1e-6f);
            float v[8] = {a.x*inv, a.y*inv, a.z*inv, a.w*inv,
                          b.x*inv, b.y*inv, b.z*inv, b.w*inv};
            const float* Mc = sM + c * 64;
            float y[8];
            #pragma unroll
            for (int k = 0; k < 8; ++k) {
                float s = 0.f;
                #pragma unroll
                for (int m = 0; m < 8; ++m) s += Mc[k * 8 + m] * v[m];
                y[k] = 0.5f * s * (1.0f + erff(s * 0.70710678118f));
            }
            float4* gp = (float4*)(sG + r * ROW + c * 8);
            gp[0] = make_float4(y[0], y[1], y[2], y[3]);
            gp[1] = make_float4(y[4], y[5], y[6], y[7]);
        }
        __syncthreads();

        // ---- GEMM: acc[4][4] over K=128
        float acc[4][4];
        #pragma unroll
        for (int r = 0; r < 4; ++r)
            #pragma unroll
            for (int c = 0; c < 4; ++c) acc[r][c] = 0.f;

        for (int k = 0; k < ROW; k += 4) {
            float ga[4][4];
            #pragma unroll
            for (int r = 0; r < 4; ++r) {
                const float4 gv = *(const float4*)(sG + (rb + r) * ROW + k);
                ga[r][0] = gv.x; ga[r][1] = gv.y; ga[r][2] = gv.z; ga[r][3] = gv.w;
            }
            #pragma unroll
            for (int kk = 0; kk < 4; ++kk) {
                const float4 wv = *(const float4*)(sW2T + (k + kk) * ROW + cb);
                #pragma unroll
                for (int r = 0; r < 4; ++r) {
                    acc[r][0] += ga[r][kk] * wv.x;
                    acc[r][1] += ga[r][kk] * wv.y;
                    acc[r][2] += ga[r][kk] * wv.z;
                    acc[r][3] += ga[r][kk] * wv.w;
                }
            }
        }

        // ---- epilogue: + bias, coalesced float4 stores
        const float4 bv = *(const float4*)(sBias + cb);
        #pragma unroll
        for (int r = 0; r < 4; ++r) {
            float4 st;
            st.x = acc[r][0] + bv.x;
            st.y = acc[r][1] + bv.y;
            st.z = acc[r][2] + bv.z;
            st.w = acc[r][3] + bv.w;
            *(float4*)(out + (row0 + rb + r) * ROW + cb) = st;
        }
        __syncthreads();   // protect sG before next tile's preprocess
    }
}

extern "C" void kernel_launch(void* const* d_in, const int* in_sizes, int n_in,
                              void* d_out, int out_size, void* d_ws, size_t ws_size,
                              hipStream_t stream)
{
    const float* x        = (const float*)d_in[0];
    const float* ln_scale = (const float*)d_in[1];
    const float* rotor    = (const float*)d_in[2];
    const float* w        = (const float*)d_in[3];
    const float* bias     = (const float*)d_in[4];
    float* out = (float*)d_out;
    float* ws  = (float*)d_ws;

    precompute_kernel<<<dim3(1), dim3(256), 0, stream>>>(rotor, w, ws);

    const int nrows  = in_sizes[0] / (CH * DIM);   // 131072
    const int ntiles = nrows / TILE_ROWS;          // 2048

    const size_t smem = (size_t)(16384 + 8192 + 1024 + 128 + 16) * sizeof(float);
    (void)hipFuncSetAttribute((const void*)fused_kernel,
                              hipFuncAttributeMaxDynamicSharedMemorySize,
                              (int)smem);
    fused_kernel<<<dim3(NBLOCKS), dim3(BLK), smem, stream>>>(
        x, ln_scale, bias, ws, out, ntiles);
}

// Round 2
// 58.727 us; speedup vs baseline: 3.3309x; 3.3309x over previous
//
#include <hip/hip_runtime.h>
#include <math.h>

#define CH 16
#define DIM 8
#define ROW 128            // CH*DIM
#define TILE_ROWS 64
#define BLK 256            // 4 waves
#define NBLOCKS 1024

typedef __attribute__((ext_vector_type(8))) short bf16x8;
typedef __attribute__((ext_vector_type(4))) float f32x4;

// Cayley sign for Cl(3,0): e_a * e_b = csign(a,b) * e_{a^b}
__device__ __forceinline__ float csign(int a, int b) {
    int s = 0;
    int aa = a >> 1;
    while (aa) { s ^= (__popc(aa & b) & 1); aa >>= 1; }
    return s ? -1.0f : 1.0f;
}

// float -> bf16 (round-to-nearest-even)
__device__ __forceinline__ unsigned short f2bf(float f) {
    union { float f; unsigned u; } x; x.f = f;
    unsigned r = x.u + 0x7FFF + ((x.u >> 16) & 1);
    return (unsigned short)(r >> 16);
}

// ---------------------------------------------------------------------------
// Precompute (1 block, 256 threads):
//   ws[0..1024) fp32      : M^T[(k*8+m)*16 + c] -- per-channel 8x8 sandwich
//   (ushort*)(ws+1024)    : W2R[out_f][in_f] bf16, 128x128
//      out[b,out_f] = sum_in g[b,in_f] * W2R[out_f][in_f]
// ---------------------------------------------------------------------------
__global__ void precompute_kernel(const float* __restrict__ rotor,
                                  const float* __restrict__ w,
                                  float* __restrict__ ws)
{
    const int t = threadIdx.x;

    if (t < CH) {
        const int c = t;
        float r[8];
        float nn = 0.f;
        #pragma unroll
        for (int i = 0; i < 8; ++i) { r[i] = rotor[c * 8 + i]; nn += r[i] * r[i]; }
        const float inv = rsqrtf(nn + 1e-6f);
        #pragma unroll
        for (int i = 0; i < 8; ++i) r[i] *= inv;

        const float REVv[8] = {1.f, 1.f, 1.f, -1.f, 1.f, -1.f, -1.f, -1.f};
        float rr[8];
        #pragma unroll
        for (int j = 0; j < 8; ++j) rr[j] = r[j] * REVv[j];

        float L[8][8], R[8][8];
        #pragma unroll
        for (int a = 0; a < 8; ++a)
            #pragma unroll
            for (int b = 0; b < 8; ++b) { L[a][b] = 0.f; R[a][b] = 0.f; }

        #pragma unroll
        for (int i = 0; i < 8; ++i)
            #pragma unroll
            for (int j = 0; j < 8; ++j) {
                const float s = csign(i, j);
                L[i ^ j][j] += r[i] * s;
                R[i ^ j][i] += rr[j] * s;
            }

        #pragma unroll
        for (int k = 0; k < 8; ++k)
            #pragma unroll
            for (int m = 0; m < 8; ++m) {
                float acc = 0.f;
                #pragma unroll
                for (int i = 0; i < 8; ++i) acc += R[k][i] * L[i][m];
                ws[(k * 8 + m) * 16 + c] = acc;   // transposed: [km][c]
            }
    }

    unsigned short* w2r = (unsigned short*)(ws + 1024);
    for (int idx = t; idx < ROW * ROW; idx += blockDim.x) {
        const int outf = idx >> 7;
        const int inf  = idx & 127;
        const int j  = inf & 7,  ci = inf >> 3;
        const int kb = outf & 7, o  = outf >> 3;
        const int i  = kb ^ j;
        w2r[idx] = f2bf(w[(o * CH + ci) * 8 + i] * csign(i, j));
    }
}

// ---------------------------------------------------------------------------
// Fused: per 64-row tile:
//  1) LN -> rotor 8x8 matvec -> exact GELU -> bf16 -> swizzled LDS g-tile
//  2) out[64][128] = g @ W2R^T via mfma_f32_16x16x32_bf16; W2R in registers
// ---------------------------------------------------------------------------
__global__ __launch_bounds__(BLK, 4) void fused_kernel(
        const float* __restrict__ x,
        const float* __restrict__ ln_scale,
        const float* __restrict__ bias,
        const float* __restrict__ ws,
        float* __restrict__ out,
        int ntiles)
{
    __shared__ unsigned short sG[TILE_ROWS * ROW];   // 16 KiB, swizzled
    __shared__ float sM[1024];                       // M^T[km][c]
    __shared__ float sScale[CH];

    const int t    = threadIdx.x;
    const int lane = t & 63;
    const int wave = t >> 6;

    for (int i = t; i < 1024 / 4; i += BLK)
        ((float4*)sM)[i] = ((const float4*)ws)[i];
    if (t < CH) sScale[t] = ln_scale[t];

    // B fragments in registers: wave covers cols [wave*32, wave*32+32)
    const unsigned short* w2r = (const unsigned short*)(ws + 1024);
    const int colb = wave * 32;
    const int lcol = lane & 15;
    const int lkg  = lane >> 4;

    bf16x8 Bf[2][4];
    #pragma unroll
    for (int ct = 0; ct < 2; ++ct)
        #pragma unroll
        for (int ks = 0; ks < 4; ++ks) {
            const int col = colb + ct * 16 + lcol;
            const int kb  = ks * 32 + lkg * 8;
            Bf[ct][ks] = *(const bf16x8*)(w2r + col * ROW + kb);
        }

    float bv[2];
    bv[0] = bias[colb + lcol];
    bv[1] = bias[colb + 16 + lcol];

    __syncthreads();

    const int pr = t >> 4;   // preprocess row (this iter 0)
    const int pc = t & 15;   // preprocess channel (fixed per thread)

    for (int tile = blockIdx.x; tile < ntiles; tile += gridDim.x) {
        const size_t row0 = (size_t)tile * TILE_ROWS;

        // ---- preprocess: 1024 multivectors / 256 threads = 4 each
        #pragma unroll
        for (int it = 0; it < (TILE_ROWS * CH) / BLK; ++it) {
            const int r = pr + it * 16;
            const float4* xp = (const float4*)(x + ((row0 + r) * CH + pc) * DIM);
            const float4 a = xp[0];
            const float4 b = xp[1];
            const float nn = a.x*a.x + a.y*a.y + a.z*a.z + a.w*a.w
                           + b.x*b.x + b.y*b.y + b.z*b.z + b.w*b.w;
            const float inv = sScale[pc] * rsqrtf(nn + 1e-6f);
            const float v[8] = {a.x*inv, a.y*inv, a.z*inv, a.w*inv,
                                b.x*inv, b.y*inv, b.z*inv, b.w*inv};
            bf16x8 pk;
            #pragma unroll
            for (int k = 0; k < 8; ++k) {
                float s = 0.f;
                #pragma unroll
                for (int m = 0; m < 8; ++m) s += sM[(k * 8 + m) * 16 + pc] * v[m];
                const float y = 0.5f * s * (1.0f + erff(s * 0.70710678118f));
                pk[k] = (short)f2bf(y);
            }
            const int chunk = pc ^ (r & 15);               // XOR swizzle
            *(bf16x8*)(sG + r * ROW + chunk * 8) = pk;
        }
        __syncthreads();

        // ---- MFMA GEMM: each wave 64 rows x 32 cols
        f32x4 acc[4][2];
        #pragma unroll
        for (int rt = 0; rt < 4; ++rt)
            #pragma unroll
            for (int ct = 0; ct < 2; ++ct)
                acc[rt][ct] = (f32x4){0.f, 0.f, 0.f, 0.f};

        #pragma unroll
        for (int rt = 0; rt < 4; ++rt) {
            const int row = rt * 16 + lcol;
            #pragma unroll
            for (int ks = 0; ks < 4; ++ks) {
                const int chunk = (ks * 4 + lkg) ^ (row & 15);
                const bf16x8 afr = *(const bf16x8*)(sG + row * ROW + chunk * 8);
                acc[rt][0] = __builtin_amdgcn_mfma_f32_16x16x32_bf16(
                                 afr, Bf[0][ks], acc[rt][0], 0, 0, 0);
                acc[rt][1] = __builtin_amdgcn_mfma_f32_16x16x32_bf16(
                                 afr, Bf[1][ks], acc[rt][1], 0, 0, 0);
            }
        }

        // ---- epilogue: C/D layout col=lane&15, row=(lane>>4)*4+j
        #pragma unroll
        for (int rt = 0; rt < 4; ++rt) {
            const size_t rbase = row0 + rt * 16 + lkg * 4;
            #pragma unroll
            for (int ct = 0; ct < 2; ++ct) {
                const int col = colb + ct * 16 + lcol;
                #pragma unroll
                for (int j = 0; j < 4; ++j)
                    out[(rbase + j) * ROW + col] = acc[rt][ct][j] + bv[ct];
            }
        }
        __syncthreads();   // protect sG before next tile's preprocess
    }
}

extern "C" void kernel_launch(void* const* d_in, const int* in_sizes, int n_in,
                              void* d_out, int out_size, void* d_ws, size_t ws_size,
                              hipStream_t stream)
{
    const float* x        = (const float*)d_in[0];
    const float* ln_scale = (const float*)d_in[1];
    const float* rotor    = (const float*)d_in[2];
    const float* w        = (const float*)d_in[3];
    const float* bias     = (const float*)d_in[4];
    float* out = (float*)d_out;
    float* ws  = (float*)d_ws;

    precompute_kernel<<<dim3(1), dim3(256), 0, stream>>>(rotor, w, ws);

    const int nrows  = in_sizes[0] / (CH * DIM);   // 131072
    const int ntiles = nrows / TILE_ROWS;          // 2048

    fused_kernel<<<dim3(NBLOCKS), dim3(BLK), 0, stream>>>(
        x, ln_scale, bias, ws, out, ntiles);
}